// Round 8
// baseline (6802.383 us; speedup 1.0000x reference)
//
#include <hip/hip_runtime.h>

#define TT 1000
#define FF 20
#define HH 256
#define OO 200
#define ZR 256           // zero-row index in padded int32 tables (257 rows x 256 cols)

typedef unsigned int uint;
typedef unsigned long long ull;

__device__ __forceinline__ int rfl(int v) { return __builtin_amdgcn_readfirstlane(v); }

#define INV30 9.31322574615478515625e-10   // 2^-30, exact in double

// N-deep signed toggle batch: rows from wave-uniform 32-bit toggle word m, sign from
// current mask cur (+ if now active, - if now inactive). Empty slots hit zero row ZR.
// All mask/row/sign math on the scalar pipe; N int4 loads in flight; exact int64 acc.
template<int N>
__device__ __forceinline__ void gstepI(const int* __restrict__ tab, uint& m, uint cur,
                                       int rowbase, int cx, long long* acc) {
    const int* p[N];
    int sm[N];
#pragma unroll
    for (int u = 0; u < N; ++u) {
        int bb = __ffs((int)m);
        int k  = (bb ? bb : 1) - 1;
        int row = rfl(m ? (rowbase + k) : ZR);
        int pos = rfl(m ? (int)((cur >> k) & 1u) : 1);
        sm[u] = pos ? 0 : -1;
        p[u]  = tab + ((size_t)row << 8);
        m &= (m - 1u);
    }
    int4 v[N];
#pragma unroll
    for (int u = 0; u < N; ++u) v[u] = *(const int4*)(p[u] + cx);
#pragma unroll
    for (int u = 0; u < N; ++u) {
        acc[0] += (long long)((v[u].x ^ sm[u]) - sm[u]);
        acc[1] += (long long)((v[u].y ^ sm[u]) - sm[u]);
        acc[2] += (long long)((v[u].z ^ sm[u]) - sm[u]);
        acc[3] += (long long)((v[u].w ^ sm[u]) - sm[u]);
    }
}

// Adaptive-depth toggle gather into a PERSISTENT register accumulator (exact int64).
__device__ __forceinline__ void gatherR(const int* __restrict__ tab, uint m, uint cur,
                                        int rowbase, int cx, long long* acc) {
    while (m) {
        int pc = rfl(__popc(m));
        if (pc > 12)      gstepI<16>(tab, m, cur, rowbase, cx, acc);
        else if (pc > 8)  gstepI<12>(tab, m, cur, rowbase, cx, acc);
        else if (pc > 4)  gstepI<8>(tab, m, cur, rowbase, cx, acc);
        else              gstepI<4>(tab, m, cur, rowbase, cx, acc);
    }
}

// Tables are column-PERMUTED in prep: position q*4+c holds original column c*64+q.
// So lane q's int4 load at cx=q*4 yields original columns {q, 64+q, 128+q, 192+q},
// making both the LDS publish (slot c*64+q, lane stride 8B) and the consumer read
// (slot j, lane stride 8B) bank-conflict-free.

__global__ __launch_bounds__(1024, 4) void snn_main(
    const float* __restrict__ x,
    const float* __restrict__ W1, const float* __restrict__ b1,
    const float* __restrict__ beta1,
    const float* __restrict__ b2, const float* __restrict__ beta2,
    const int* __restrict__ V1q, const int* __restrict__ V2q,
    const int* __restrict__ W2Tq, const int* __restrict__ WTq,
    const float* __restrict__ alpha_out, const float* __restrict__ beta_out,
    float* __restrict__ out)
{
    __shared__ float w1t_s[FF * HH];     // W1 transposed [f][h]
    __shared__ float wx_s[2][HH];        // b1 + W1 x_t, double-buffered by t parity
    __shared__ float xts[2][FF];         // x[t] double buffer
    __shared__ long long pW2q[8][HH];    // published int64 drive partials (word e)
    __shared__ long long pV1q[8][HH];    // linear column layout -> 8B lane stride
    __shared__ long long pV2q[8][HH];
    __shared__ long long pOq[8][HH];
    __shared__ uint m1w[8], t1w[8];      // current + toggle masks (8 x 32-bit words)
    __shared__ uint m2w[8], t2w[8];

    const int tid = threadIdx.x;
    const int wv  = tid >> 6;
    const int cq  = tid & 63;
    const int b   = blockIdx.x;
    const float* xg = x + (size_t)b * TT * FF;

    // ---- init ----
    for (int idx = tid; idx < FF * HH; idx += 1024) {
        int h = idx / FF, f = idx - h * FF;
        w1t_s[f * HH + h] = W1[idx];
    }
    if (tid < FF) { xts[0][tid] = xg[tid]; xts[1][tid] = xg[FF + tid]; }
    if (tid < 8) { m1w[tid] = 0u; t1w[tid] = 0u; m2w[tid] = 0u; t2w[tid] = 0u; }
    for (int idx = tid; idx < 8 * HH; idx += 1024) {
        ((long long*)pW2q)[idx] = 0; ((long long*)pV1q)[idx] = 0;
        ((long long*)pV2q)[idx] = 0; ((long long*)pOq)[idx]  = 0;
    }

    // persistent register drive accumulators; role fixed per wave:
    //   wv 0-7 : accC = W2T word wv   | accE = WT word wv
    //   wv 8-15: accC = V1  word wv-8 | accE = V2 word wv-8
    long long accC[4] = {0, 0, 0, 0};
    long long accE[4] = {0, 0, 0, 0};

    float syn1 = 0.f, mem1 = 0.f, syn2 = 0.f, mem2 = 0.f;
    float b2r = 0.f, beta1r = 0.f, beta2r = 0.f;
    bool spk1 = false, spk2 = false;
    if (tid < HH) { beta1r = beta1[tid]; beta2r = beta2[tid]; b2r = b2[tid]; }
    float b1r2 = 0.f;
    if (tid >= HH && tid < 2 * HH) b1r2 = b1[tid - HH];

    float synO[4] = {0,0,0,0}, memO[4] = {0,0,0,0}, accO[4] = {0,0,0,0};
    float aOr[4] = {0,0,0,0}, bOr[4] = {0,0,0,0};
    bool  spkO[4] = {false,false,false,false};
    if (wv == 15) {
#pragma unroll
        for (int r = 0; r < 4; ++r) {
            int o = cq + (r << 6);
            if (o < OO) { aOr[r] = alpha_out[o]; bOr[r] = beta_out[o]; }
        }
    }
    __syncthreads();
    if (tid < HH) {   // wx for t=0
        float wx = b1[tid];
#pragma unroll
        for (int f = 0; f < FF; ++f) wx = fmaf(xts[0][f], w1t_s[f * HH + tid], wx);
        wx_s[0][tid] = wx;
    }
    __syncthreads();

    for (int t = 0; t < TT; ++t) {
        // ---- B: layer-1 update (waves 0-3); emit m1/t1 mask words ----
        if (tid < HH) {
            long long a = pV1q[0][tid] + pV1q[1][tid] + pV1q[2][tid] + pV1q[3][tid]
                        + pV1q[4][tid] + pV1q[5][tid] + pV1q[6][tid] + pV1q[7][tid];
            float g1 = (float)((double)a * INV30);
            syn1 = fmaf(0.95f, syn1, wx_s[t & 1][tid] + g1);
            mem1 = fmaf(beta1r, mem1, syn1) - (spk1 ? 1.f : 0.f);
            spk1 = mem1 > 1.0f;
            ull bal = __ballot(spk1 ? 1 : 0);
            if (cq == 0) {
                uint n0 = (uint)bal, n1 = (uint)(bal >> 32);
                t1w[2*wv]   = m1w[2*wv]   ^ n0;
                t1w[2*wv+1] = m1w[2*wv+1] ^ n1;
                m1w[2*wv]   = n0;
                m1w[2*wv+1] = n1;
            }
        }
        __syncthreads();
        // ---- C: toggle-gathers on t1: W2T (waves 0-7), V1 (waves 8-15) ----
        if (wv < 8) {
            uint tm = (uint)rfl((int)t1w[wv]);
            if (tm) {
                uint cm = (uint)rfl((int)m1w[wv]);
                gatherR(W2Tq, tm, cm, wv << 5, cq << 2, accC);
#pragma unroll
                for (int c = 0; c < 4; ++c) pW2q[wv][(c << 6) | cq] = accC[c];
            }
        } else {
            int e = wv - 8;
            uint tm = (uint)rfl((int)t1w[e]);
            if (tm) {
                uint cm = (uint)rfl((int)m1w[e]);
                gatherR(V1q, tm, cm, e << 5, cq << 2, accC);
#pragma unroll
                for (int c = 0; c < 4; ++c) pV1q[e][(c << 6) | cq] = accC[c];
            }
        }
        __syncthreads();
        // ---- D: layer-2 update (waves 0-3) + wx(t+1) (waves 4-7) + x prefetch (wave 8) ----
        if (tid < HH) {
            long long a1 = pW2q[0][tid] + pW2q[1][tid] + pW2q[2][tid] + pW2q[3][tid]
                         + pW2q[4][tid] + pW2q[5][tid] + pW2q[6][tid] + pW2q[7][tid];
            long long a2 = pV2q[0][tid] + pV2q[1][tid] + pV2q[2][tid] + pV2q[3][tid]
                         + pV2q[4][tid] + pV2q[5][tid] + pV2q[6][tid] + pV2q[7][tid];
            float gA = (float)((double)a1 * INV30);
            float gB = (float)((double)a2 * INV30);
            syn2 = fmaf(0.95f, syn2, b2r + gA + gB);
            mem2 = fmaf(beta2r, mem2, syn2) - (spk2 ? 1.f : 0.f);
            spk2 = mem2 > 1.0f;
            ull bal = __ballot(spk2 ? 1 : 0);
            if (cq == 0) {
                uint n0 = (uint)bal, n1 = (uint)(bal >> 32);
                t2w[2*wv]   = m2w[2*wv]   ^ n0;
                t2w[2*wv+1] = m2w[2*wv+1] ^ n1;
                m2w[2*wv]   = n0;
                m2w[2*wv+1] = n1;
            }
        } else if (tid < 2 * HH) {
            if ((t + 1) < TT) {
                int j2 = tid - HH;
                const float* xx = xts[(t + 1) & 1];
                float wx = b1r2;
#pragma unroll
                for (int f = 0; f < FF; ++f) wx = fmaf(xx[f], w1t_s[f * HH + j2], wx);
                wx_s[(t + 1) & 1][j2] = wx;
            }
        } else if (wv == 8 && cq < FF) {
            if ((t + 2) < TT) xts[t & 1][cq] = xg[(size_t)(t + 2) * FF + cq];
        }
        __syncthreads();
        // ---- E: toggle-gathers on t2: WT (waves 0-7), V2 (waves 8-15) ----
        if (wv < 8) {
            uint tm = (uint)rfl((int)t2w[wv]);
            if (tm) {
                uint cm = (uint)rfl((int)m2w[wv]);
                gatherR(WTq, tm, cm, wv << 5, cq << 2, accE);
#pragma unroll
                for (int c = 0; c < 4; ++c) pOq[wv][(c << 6) | cq] = accE[c];
            }
        } else {
            int e = wv - 8;
            uint tm = (uint)rfl((int)t2w[e]);
            if (tm) {
                uint cm = (uint)rfl((int)m2w[e]);
                gatherR(V2q, tm, cm, e << 5, cq << 2, accE);
#pragma unroll
                for (int c = 0; c < 4; ++c) pV2q[e][(c << 6) | cq] = accE[c];
            }
        }
        __syncthreads();
        // ---- F: output layer (wave 15; overlaps B(t+1) on waves 0-3) ----
        if (wv == 15) {
            float mmax = -3.402823466e38f;
#pragma unroll
            for (int r = 0; r < 4; ++r) {
                int o = cq + (r << 6);
                if (o < OO) {
                    long long a = pOq[0][o] + pOq[1][o] + pOq[2][o] + pOq[3][o]
                                + pOq[4][o] + pOq[5][o] + pOq[6][o] + pOq[7][o];
                    float ot = (float)((double)a * INV30);
                    synO[r] = fmaf(aOr[r], synO[r], ot);
                    memO[r] = fmaf(bOr[r], memO[r], synO[r]) - (spkO[r] ? 1.f : 0.f);
                    spkO[r] = memO[r] > 1.0f;
                    mmax = fmaxf(mmax, memO[r]);
                }
            }
#pragma unroll
            for (int off = 32; off; off >>= 1) mmax = fmaxf(mmax, __shfl_xor(mmax, off, 64));
            float ex[4]; float se = 0.f;
#pragma unroll
            for (int r = 0; r < 4; ++r) {
                int o = cq + (r << 6);
                ex[r] = (o < OO) ? expf(memO[r] - mmax) : 0.f;
                se += ex[r];
            }
#pragma unroll
            for (int off = 32; off; off >>= 1) se += __shfl_xor(se, off, 64);
            if (t > 10) {
#pragma unroll
                for (int r = 0; r < 4; ++r) accO[r] += ex[r] / se;
            }
        }
        // no barrier: pOq's next writers (E(t+1)) sit behind the D(t+1) barrier, which
        // wave 15 only reaches after finishing F(t).
    }

    if (wv == 15) {
#pragma unroll
        for (int r = 0; r < 4; ++r) {
            int o = cq + (r << 6);
            if (o < OO) out[(size_t)b * OO + o] = accO[r];
        }
    }
}

// one-shot prep: padded 257x256 int32 fixed-point (2^30) tables, zero diagonal
// (V1q/V2q), zero row 256. Columns PERMUTED: position q*4+c holds original
// column c*64+q (see note at gatherR).
__global__ void prep_kernel(const float* __restrict__ Vrec1, const float* __restrict__ Vrec2,
                            const float* __restrict__ W2, const float* __restrict__ Wout,
                            int* __restrict__ V1q, int* __restrict__ V2q,
                            int* __restrict__ W2Tq, int* __restrict__ WTq) {
    int idx = blockIdx.x * blockDim.x + threadIdx.x;   // 257*256 entries
    if (idx >= 257 * 256) return;
    int r = idx >> 8, i = idx & 255;
    int q = i >> 2, c = i & 3;
    int sc = (c << 6) | q;                 // original column this slot holds
    float v1 = 0.f, v2 = 0.f, w2 = 0.f, wo = 0.f;
    if (r < 256) {
        if (r != sc) { v1 = Vrec1[r * HH + sc]; v2 = Vrec2[r * HH + sc]; }
        w2 = W2[sc * HH + r];
        if (sc < OO) wo = Wout[sc * HH + r];
    }
    const float S = 1073741824.0f;   // 2^30
    V1q[idx]  = __float2int_rn(v1 * S);
    V2q[idx]  = __float2int_rn(v2 * S);
    W2Tq[idx] = __float2int_rn(w2 * S);
    WTq[idx]  = __float2int_rn(wo * S);
}

extern "C" void kernel_launch(void* const* d_in, const int* in_sizes, int n_in,
                              void* d_out, int out_size, void* d_ws, size_t ws_size,
                              hipStream_t stream) {
    const float* x       = (const float*)d_in[0];
    const float* W1      = (const float*)d_in[1];
    const float* b1      = (const float*)d_in[2];
    const float* Vrec1   = (const float*)d_in[3];
    const float* beta1   = (const float*)d_in[4];
    const float* W2      = (const float*)d_in[5];
    const float* b2      = (const float*)d_in[6];
    const float* Vrec2   = (const float*)d_in[7];
    const float* beta2   = (const float*)d_in[8];
    const float* Wout    = (const float*)d_in[9];
    const float* alpha_o = (const float*)d_in[10];
    const float* beta_o  = (const float*)d_in[11];

    const int TBL = 257 * 256;       // int32 per padded table
    int* V1q  = (int*)d_ws;
    int* V2q  = V1q + TBL;
    int* W2Tq = V2q + TBL;
    int* WTq  = W2Tq + TBL;          // total ~1.05 MB of ws

    prep_kernel<<<(TBL + 255) / 256, 256, 0, stream>>>(Vrec1, Vrec2, W2, Wout,
                                                       V1q, V2q, W2Tq, WTq);
    snn_main<<<128, 1024, 0, stream>>>(x, W1, b1, beta1, b2, beta2,
                                       V1q, V2q, W2Tq, WTq,
                                       alpha_o, beta_o, (float*)d_out);
}

// Round 9
// 4942.550 us; speedup vs baseline: 1.3763x; 1.3763x over previous
//
#include <hip/hip_runtime.h>

#define TT 1000
#define FF 20
#define HH 256
#define OO 200
#define ZR 256           // zero-row index in padded int32 tables (257 rows x 256 cols)

typedef unsigned int uint;
typedef unsigned long long ull;

__device__ __forceinline__ int rfl(int v) { return __builtin_amdgcn_readfirstlane(v); }

#define INV30 9.31322574615478515625e-10   // 2^-30, exact in double

// N-deep signed toggle batch: rows from wave-uniform 32-bit toggle word m, sign from
// current mask cur (+ if now active, - if now inactive). Empty slots hit zero row ZR.
// All mask/row/sign math on the scalar pipe; N int4 loads in flight; exact int64 acc.
template<int N>
__device__ __forceinline__ void gstepI(const int* __restrict__ tab, uint& m, uint cur,
                                       int rowbase, int cx, long long* acc) {
    const int* p[N];
    int sm[N];
#pragma unroll
    for (int u = 0; u < N; ++u) {
        int bb = __ffs((int)m);
        int k  = (bb ? bb : 1) - 1;
        int row = rfl(m ? (rowbase + k) : ZR);
        int pos = rfl(m ? (int)((cur >> k) & 1u) : 1);
        sm[u] = pos ? 0 : -1;
        p[u]  = tab + ((size_t)row << 8);
        m &= (m - 1u);
    }
    int4 v[N];
#pragma unroll
    for (int u = 0; u < N; ++u) v[u] = *(const int4*)(p[u] + cx);
#pragma unroll
    for (int u = 0; u < N; ++u) {
        acc[0] += (long long)((v[u].x ^ sm[u]) - sm[u]);
        acc[1] += (long long)((v[u].y ^ sm[u]) - sm[u]);
        acc[2] += (long long)((v[u].z ^ sm[u]) - sm[u]);
        acc[3] += (long long)((v[u].w ^ sm[u]) - sm[u]);
    }
}

// Adaptive-depth toggle gather into a phase-local register accumulator (exact int64).
__device__ __forceinline__ void gatherR(const int* __restrict__ tab, uint m, uint cur,
                                        int rowbase, int cx, long long* acc) {
    while (m) {
        int pc = rfl(__popc(m));
        if (pc > 12)      gstepI<16>(tab, m, cur, rowbase, cx, acc);
        else if (pc > 8)  gstepI<12>(tab, m, cur, rowbase, cx, acc);
        else if (pc > 4)  gstepI<8>(tab, m, cur, rowbase, cx, acc);
        else              gstepI<4>(tab, m, cur, rowbase, cx, acc);
    }
}

// Tables are column-PERMUTED in prep: position q*4+c holds original column c*64+q.
// So lane q's int4 load at cx=q*4 yields original columns {q, 64+q, 128+q, 192+q},
// making the LDS drive update (slot c*64+q, lane stride 8B) and the consumer read
// (slot j, lane stride 8B) both bank-conflict-free.

__global__ __launch_bounds__(1024) void snn_main(
    const float* __restrict__ x,
    const float* __restrict__ W1, const float* __restrict__ b1,
    const float* __restrict__ beta1,
    const float* __restrict__ b2, const float* __restrict__ beta2,
    const int* __restrict__ V1q, const int* __restrict__ V2q,
    const int* __restrict__ W2Tq, const int* __restrict__ WTq,
    const float* __restrict__ alpha_out, const float* __restrict__ beta_out,
    float* __restrict__ out)
{
    __shared__ float w1t_s[FF * HH];     // W1 transposed [f][h]
    __shared__ float wx_s[2][HH];        // b1 + W1 x_t, double-buffered by t parity
    __shared__ float xts[2][FF];         // x[t] double buffer
    __shared__ long long pW2q[8][HH];    // persistent int64 drive partials (word e),
    __shared__ long long pV1q[8][HH];    // updated in-place by the owning wave
    __shared__ long long pV2q[8][HH];
    __shared__ long long pOq[8][HH];
    __shared__ uint m1w[8], t1w[8];      // current + toggle masks (8 x 32-bit words)
    __shared__ uint m2w[8], t2w[8];

    const int tid = threadIdx.x;
    const int wv  = tid >> 6;
    const int cq  = tid & 63;
    const int b   = blockIdx.x;
    const float* xg = x + (size_t)b * TT * FF;

    // ---- init ----
    for (int idx = tid; idx < FF * HH; idx += 1024) {
        int h = idx / FF, f = idx - h * FF;
        w1t_s[f * HH + h] = W1[idx];
    }
    if (tid < FF) { xts[0][tid] = xg[tid]; xts[1][tid] = xg[FF + tid]; }
    if (tid < 8) { m1w[tid] = 0u; t1w[tid] = 0u; m2w[tid] = 0u; t2w[tid] = 0u; }
    for (int idx = tid; idx < 8 * HH; idx += 1024) {
        ((long long*)pW2q)[idx] = 0; ((long long*)pV1q)[idx] = 0;
        ((long long*)pV2q)[idx] = 0; ((long long*)pOq)[idx]  = 0;
    }

    float syn1 = 0.f, mem1 = 0.f, syn2 = 0.f, mem2 = 0.f;
    float b2r = 0.f, beta1r = 0.f, beta2r = 0.f;
    bool spk1 = false, spk2 = false;
    if (tid < HH) { beta1r = beta1[tid]; beta2r = beta2[tid]; b2r = b2[tid]; }
    float b1r2 = 0.f;
    if (tid >= HH && tid < 2 * HH) b1r2 = b1[tid - HH];

    float synO[4] = {0,0,0,0}, memO[4] = {0,0,0,0}, accO[4] = {0,0,0,0};
    float aOr[4] = {0,0,0,0}, bOr[4] = {0,0,0,0};
    bool  spkO[4] = {false,false,false,false};
    if (wv == 15) {
#pragma unroll
        for (int r = 0; r < 4; ++r) {
            int o = cq + (r << 6);
            if (o < OO) { aOr[r] = alpha_out[o]; bOr[r] = beta_out[o]; }
        }
    }
    __syncthreads();
    if (tid < HH) {   // wx for t=0
        float wx = b1[tid];
#pragma unroll
        for (int f = 0; f < FF; ++f) wx = fmaf(xts[0][f], w1t_s[f * HH + tid], wx);
        wx_s[0][tid] = wx;
    }
    __syncthreads();

    for (int t = 0; t < TT; ++t) {
        // ---- B: layer-1 update (waves 0-3); emit m1/t1 mask words ----
        if (tid < HH) {
            long long a = pV1q[0][tid] + pV1q[1][tid] + pV1q[2][tid] + pV1q[3][tid]
                        + pV1q[4][tid] + pV1q[5][tid] + pV1q[6][tid] + pV1q[7][tid];
            float g1 = (float)((double)a * INV30);
            syn1 = fmaf(0.95f, syn1, wx_s[t & 1][tid] + g1);
            mem1 = fmaf(beta1r, mem1, syn1) - (spk1 ? 1.f : 0.f);
            spk1 = mem1 > 1.0f;
            ull bal = __ballot(spk1 ? 1 : 0);
            if (cq == 0) {
                uint n0 = (uint)bal, n1 = (uint)(bal >> 32);
                t1w[2*wv]   = m1w[2*wv]   ^ n0;
                t1w[2*wv+1] = m1w[2*wv+1] ^ n1;
                m1w[2*wv]   = n0;
                m1w[2*wv+1] = n1;
            }
        }
        __syncthreads();
        // ---- C: toggle-updates on t1: W2T drives (waves 0-7), V1 drives (waves 8-15) ----
        if (wv < 8) {
            uint tm = (uint)rfl((int)t1w[wv]);
            if (tm) {
                uint cm = (uint)rfl((int)m1w[wv]);
                long long acc[4];
#pragma unroll
                for (int c = 0; c < 4; ++c) acc[c] = pW2q[wv][(c << 6) | cq];
                gatherR(W2Tq, tm, cm, wv << 5, cq << 2, acc);
#pragma unroll
                for (int c = 0; c < 4; ++c) pW2q[wv][(c << 6) | cq] = acc[c];
            }
        } else {
            int e = wv - 8;
            uint tm = (uint)rfl((int)t1w[e]);
            if (tm) {
                uint cm = (uint)rfl((int)m1w[e]);
                long long acc[4];
#pragma unroll
                for (int c = 0; c < 4; ++c) acc[c] = pV1q[e][(c << 6) | cq];
                gatherR(V1q, tm, cm, e << 5, cq << 2, acc);
#pragma unroll
                for (int c = 0; c < 4; ++c) pV1q[e][(c << 6) | cq] = acc[c];
            }
        }
        __syncthreads();
        // ---- D: layer-2 update (waves 0-3) + wx(t+1) (waves 4-7) + x prefetch (wave 8) ----
        if (tid < HH) {
            long long a1 = pW2q[0][tid] + pW2q[1][tid] + pW2q[2][tid] + pW2q[3][tid]
                         + pW2q[4][tid] + pW2q[5][tid] + pW2q[6][tid] + pW2q[7][tid];
            long long a2 = pV2q[0][tid] + pV2q[1][tid] + pV2q[2][tid] + pV2q[3][tid]
                         + pV2q[4][tid] + pV2q[5][tid] + pV2q[6][tid] + pV2q[7][tid];
            float gA = (float)((double)a1 * INV30);
            float gB = (float)((double)a2 * INV30);
            syn2 = fmaf(0.95f, syn2, b2r + gA + gB);
            mem2 = fmaf(beta2r, mem2, syn2) - (spk2 ? 1.f : 0.f);
            spk2 = mem2 > 1.0f;
            ull bal = __ballot(spk2 ? 1 : 0);
            if (cq == 0) {
                uint n0 = (uint)bal, n1 = (uint)(bal >> 32);
                t2w[2*wv]   = m2w[2*wv]   ^ n0;
                t2w[2*wv+1] = m2w[2*wv+1] ^ n1;
                m2w[2*wv]   = n0;
                m2w[2*wv+1] = n1;
            }
        } else if (tid < 2 * HH) {
            if ((t + 1) < TT) {
                int j2 = tid - HH;
                const float* xx = xts[(t + 1) & 1];
                float wx = b1r2;
#pragma unroll
                for (int f = 0; f < FF; ++f) wx = fmaf(xx[f], w1t_s[f * HH + j2], wx);
                wx_s[(t + 1) & 1][j2] = wx;
            }
        } else if (wv == 8 && cq < FF) {
            if ((t + 2) < TT) xts[t & 1][cq] = xg[(size_t)(t + 2) * FF + cq];
        }
        __syncthreads();
        // ---- E: toggle-updates on t2: WT drives (waves 0-7), V2 drives (waves 8-15) ----
        if (wv < 8) {
            uint tm = (uint)rfl((int)t2w[wv]);
            if (tm) {
                uint cm = (uint)rfl((int)m2w[wv]);
                long long acc[4];
#pragma unroll
                for (int c = 0; c < 4; ++c) acc[c] = pOq[wv][(c << 6) | cq];
                gatherR(WTq, tm, cm, wv << 5, cq << 2, acc);
#pragma unroll
                for (int c = 0; c < 4; ++c) pOq[wv][(c << 6) | cq] = acc[c];
            }
        } else {
            int e = wv - 8;
            uint tm = (uint)rfl((int)t2w[e]);
            if (tm) {
                uint cm = (uint)rfl((int)m2w[e]);
                long long acc[4];
#pragma unroll
                for (int c = 0; c < 4; ++c) acc[c] = pV2q[e][(c << 6) | cq];
                gatherR(V2q, tm, cm, e << 5, cq << 2, acc);
#pragma unroll
                for (int c = 0; c < 4; ++c) pV2q[e][(c << 6) | cq] = acc[c];
            }
        }
        __syncthreads();
        // ---- F: output layer (wave 15; overlaps B(t+1) on waves 0-3) ----
        if (wv == 15) {
            float mmax = -3.402823466e38f;
#pragma unroll
            for (int r = 0; r < 4; ++r) {
                int o = cq + (r << 6);
                if (o < OO) {
                    long long a = pOq[0][o] + pOq[1][o] + pOq[2][o] + pOq[3][o]
                                + pOq[4][o] + pOq[5][o] + pOq[6][o] + pOq[7][o];
                    float ot = (float)((double)a * INV30);
                    synO[r] = fmaf(aOr[r], synO[r], ot);
                    memO[r] = fmaf(bOr[r], memO[r], synO[r]) - (spkO[r] ? 1.f : 0.f);
                    spkO[r] = memO[r] > 1.0f;
                    mmax = fmaxf(mmax, memO[r]);
                }
            }
#pragma unroll
            for (int off = 32; off; off >>= 1) mmax = fmaxf(mmax, __shfl_xor(mmax, off, 64));
            float ex[4]; float se = 0.f;
#pragma unroll
            for (int r = 0; r < 4; ++r) {
                int o = cq + (r << 6);
                ex[r] = (o < OO) ? expf(memO[r] - mmax) : 0.f;
                se += ex[r];
            }
#pragma unroll
            for (int off = 32; off; off >>= 1) se += __shfl_xor(se, off, 64);
            if (t > 10) {
#pragma unroll
                for (int r = 0; r < 4; ++r) accO[r] += ex[r] / se;
            }
        }
        // no barrier: pOq's next writers (E(t+1)) sit behind the D(t+1) barrier, which
        // wave 15 only reaches after finishing F(t).
    }

    if (wv == 15) {
#pragma unroll
        for (int r = 0; r < 4; ++r) {
            int o = cq + (r << 6);
            if (o < OO) out[(size_t)b * OO + o] = accO[r];
        }
    }
}

// one-shot prep: padded 257x256 int32 fixed-point (2^30) tables, zero diagonal
// (V1q/V2q), zero row 256. Columns PERMUTED: position q*4+c holds original
// column c*64+q (see note above snn_main).
__global__ void prep_kernel(const float* __restrict__ Vrec1, const float* __restrict__ Vrec2,
                            const float* __restrict__ W2, const float* __restrict__ Wout,
                            int* __restrict__ V1q, int* __restrict__ V2q,
                            int* __restrict__ W2Tq, int* __restrict__ WTq) {
    int idx = blockIdx.x * blockDim.x + threadIdx.x;   // 257*256 entries
    if (idx >= 257 * 256) return;
    int r = idx >> 8, i = idx & 255;
    int q = i >> 2, c = i & 3;
    int sc = (c << 6) | q;                 // original column this slot holds
    float v1 = 0.f, v2 = 0.f, w2 = 0.f, wo = 0.f;
    if (r < 256) {
        if (r != sc) { v1 = Vrec1[r * HH + sc]; v2 = Vrec2[r * HH + sc]; }
        w2 = W2[sc * HH + r];
        if (sc < OO) wo = Wout[sc * HH + r];
    }
    const float S = 1073741824.0f;   // 2^30
    V1q[idx]  = __float2int_rn(v1 * S);
    V2q[idx]  = __float2int_rn(v2 * S);
    W2Tq[idx] = __float2int_rn(w2 * S);
    WTq[idx]  = __float2int_rn(wo * S);
}

extern "C" void kernel_launch(void* const* d_in, const int* in_sizes, int n_in,
                              void* d_out, int out_size, void* d_ws, size_t ws_size,
                              hipStream_t stream) {
    const float* x       = (const float*)d_in[0];
    const float* W1      = (const float*)d_in[1];
    const float* b1      = (const float*)d_in[2];
    const float* Vrec1   = (const float*)d_in[3];
    const float* beta1   = (const float*)d_in[4];
    const float* W2      = (const float*)d_in[5];
    const float* b2      = (const float*)d_in[6];
    const float* Vrec2   = (const float*)d_in[7];
    const float* beta2   = (const float*)d_in[8];
    const float* Wout    = (const float*)d_in[9];
    const float* alpha_o = (const float*)d_in[10];
    const float* beta_o  = (const float*)d_in[11];

    const int TBL = 257 * 256;       // int32 per padded table
    int* V1q  = (int*)d_ws;
    int* V2q  = V1q + TBL;
    int* W2Tq = V2q + TBL;
    int* WTq  = W2Tq + TBL;          // total ~1.05 MB of ws

    prep_kernel<<<(TBL + 255) / 256, 256, 0, stream>>>(Vrec1, Vrec2, W2, Wout,
                                                       V1q, V2q, W2Tq, WTq);
    snn_main<<<128, 1024, 0, stream>>>(x, W1, b1, beta1, b2, beta2,
                                       V1q, V2q, W2Tq, WTq,
                                       alpha_o, beta_o, (float*)d_out);
}

// Round 10
// 3480.844 us; speedup vs baseline: 1.9542x; 1.4199x over previous
//
#include <hip/hip_runtime.h>

#define TT 1000
#define FF 20
#define HH 256
#define OO 200
#define ZR 256           // zero-row index in padded int32 tables (257 rows x 256 cols)

typedef unsigned int uint;
typedef unsigned long long ull;

__device__ __forceinline__ int rfl(int v) { return __builtin_amdgcn_readfirstlane(v); }

#define INV30 9.31322574615478515625e-10   // 2^-30, exact in double

// ---- depth-8 signed toggle batch, fully scalarized (no local arrays -> SROA) ----
// Rows from wave-uniform 32-bit toggle word m; sign from current mask cur
// (+ if now active, - if now inactive). Empty slots hit zero row ZR.
// 8 int4 loads issued before any use; exact int64 accumulation into a0..a3.
__device__ __forceinline__ void gbatch8(const int* __restrict__ tab, uint& m, uint cur,
                                        int rowbase, int cx,
                                        long long& a0, long long& a1,
                                        long long& a2, long long& a3)
{
#define XSLOT(r, s) { int bb = __ffs((int)m); int k = (bb ? bb : 1) - 1;           \
                      r = rfl(m ? (rowbase + k) : ZR);                              \
                      s = rfl(m ? (int)((cur >> k) & 1u) : 1) ? 0 : -1;             \
                      m &= (m - 1u); }
    int r0,r1,r2,r3,r4,r5,r6,r7, s0,s1,s2,s3,s4,s5,s6,s7;
    XSLOT(r0,s0) XSLOT(r1,s1) XSLOT(r2,s2) XSLOT(r3,s3)
    XSLOT(r4,s4) XSLOT(r5,s5) XSLOT(r6,s6) XSLOT(r7,s7)
#undef XSLOT
    int4 v0 = *(const int4*)(tab + ((size_t)r0 << 8) + cx);
    int4 v1 = *(const int4*)(tab + ((size_t)r1 << 8) + cx);
    int4 v2 = *(const int4*)(tab + ((size_t)r2 << 8) + cx);
    int4 v3 = *(const int4*)(tab + ((size_t)r3 << 8) + cx);
    int4 v4 = *(const int4*)(tab + ((size_t)r4 << 8) + cx);
    int4 v5 = *(const int4*)(tab + ((size_t)r5 << 8) + cx);
    int4 v6 = *(const int4*)(tab + ((size_t)r6 << 8) + cx);
    int4 v7 = *(const int4*)(tab + ((size_t)r7 << 8) + cx);
#define XADD(v, s) { a0 += (long long)((v.x ^ s) - s); a1 += (long long)((v.y ^ s) - s); \
                     a2 += (long long)((v.z ^ s) - s); a3 += (long long)((v.w ^ s) - s); }
    XADD(v0,s0) XADD(v1,s1) XADD(v2,s2) XADD(v3,s3)
    XADD(v4,s4) XADD(v5,s5) XADD(v6,s6) XADD(v7,s7)
#undef XADD
}

// Tables are column-PERMUTED in prep: position q*4+c holds original column c*64+q.
// So lane q's int4 load at cx=q*4 yields original columns {q, 64+q, 128+q, 192+q},
// making the LDS drive update (slot c*64+q, lane stride 8B) and the consumer read
// (slot j, lane stride 8B) both bank-conflict-free.

__global__ __launch_bounds__(1024, 4) void snn_main(
    const float* __restrict__ x,
    const float* __restrict__ W1, const float* __restrict__ b1,
    const float* __restrict__ beta1,
    const float* __restrict__ b2, const float* __restrict__ beta2,
    const int* __restrict__ V1q, const int* __restrict__ V2q,
    const int* __restrict__ W2Tq, const int* __restrict__ WTq,
    const float* __restrict__ alpha_out, const float* __restrict__ beta_out,
    float* __restrict__ out)
{
    __shared__ float w1t_s[FF * HH];     // W1 transposed [f][h]
    __shared__ float wx_s[2][HH];        // b1 + W1 x_t, double-buffered by t parity
    __shared__ float xts[2][FF];         // x[t] double buffer
    __shared__ long long pW2q[8][HH];    // persistent int64 drive partials (word e),
    __shared__ long long pV1q[8][HH];    // updated in-place by the owning wave
    __shared__ long long pV2q[8][HH];
    __shared__ long long pOq[8][HH];
    __shared__ uint m1w[8], t1w[8];      // current + toggle masks (8 x 32-bit words)
    __shared__ uint m2w[8], t2w[8];

    const int tid = threadIdx.x;
    const int wv  = tid >> 6;
    const int cq  = tid & 63;
    const int b   = blockIdx.x;
    const float* xg = x + (size_t)b * TT * FF;

    // ---- init ----
    for (int idx = tid; idx < FF * HH; idx += 1024) {
        int h = idx / FF, f = idx - h * FF;
        w1t_s[f * HH + h] = W1[idx];
    }
    if (tid < FF) { xts[0][tid] = xg[tid]; xts[1][tid] = xg[FF + tid]; }
    if (tid < 8) { m1w[tid] = 0u; t1w[tid] = 0u; m2w[tid] = 0u; t2w[tid] = 0u; }
    for (int idx = tid; idx < 8 * HH; idx += 1024) {
        ((long long*)pW2q)[idx] = 0; ((long long*)pV1q)[idx] = 0;
        ((long long*)pV2q)[idx] = 0; ((long long*)pOq)[idx]  = 0;
    }

    float syn1 = 0.f, mem1 = 0.f, syn2 = 0.f, mem2 = 0.f;
    float b2r = 0.f, beta1r = 0.f, beta2r = 0.f;
    bool spk1 = false, spk2 = false;
    if (tid < HH) { beta1r = beta1[tid]; beta2r = beta2[tid]; b2r = b2[tid]; }
    float b1r2 = 0.f;
    if (tid >= HH && tid < 2 * HH) b1r2 = b1[tid - HH];

    float synO[4] = {0,0,0,0}, memO[4] = {0,0,0,0}, accO[4] = {0,0,0,0};
    float aOr[4] = {0,0,0,0}, bOr[4] = {0,0,0,0};
    bool  spkO[4] = {false,false,false,false};
    if (wv == 15) {
#pragma unroll
        for (int r = 0; r < 4; ++r) {
            int o = cq + (r << 6);
            if (o < OO) { aOr[r] = alpha_out[o]; bOr[r] = beta_out[o]; }
        }
    }
    __syncthreads();
    if (tid < HH) {   // wx for t=0
        float wx = b1[tid];
#pragma unroll
        for (int f = 0; f < FF; ++f) wx = fmaf(xts[0][f], w1t_s[f * HH + tid], wx);
        wx_s[0][tid] = wx;
    }
    __syncthreads();

    for (int t = 0; t < TT; ++t) {
        // ---- B: layer-1 update (waves 0-3); emit m1/t1 mask words ----
        if (tid < HH) {
            long long a = pV1q[0][tid] + pV1q[1][tid] + pV1q[2][tid] + pV1q[3][tid]
                        + pV1q[4][tid] + pV1q[5][tid] + pV1q[6][tid] + pV1q[7][tid];
            float g1 = (float)((double)a * INV30);
            syn1 = fmaf(0.95f, syn1, wx_s[t & 1][tid] + g1);
            mem1 = fmaf(beta1r, mem1, syn1) - (spk1 ? 1.f : 0.f);
            spk1 = mem1 > 1.0f;
            ull bal = __ballot(spk1 ? 1 : 0);
            if (cq == 0) {
                uint n0 = (uint)bal, n1 = (uint)(bal >> 32);
                t1w[2*wv]   = m1w[2*wv]   ^ n0;
                t1w[2*wv+1] = m1w[2*wv+1] ^ n1;
                m1w[2*wv]   = n0;
                m1w[2*wv+1] = n1;
            }
        }
        __syncthreads();
        // ---- C: toggle-updates on t1: W2T drives (waves 0-7), V1 drives (waves 8-15) ----
        if (wv < 8) {
            uint tm = (uint)rfl((int)t1w[wv]);
            if (tm) {
                uint cm = (uint)rfl((int)m1w[wv]);
                long long a0 = pW2q[wv][cq];
                long long a1 = pW2q[wv][64  | cq];
                long long a2 = pW2q[wv][128 | cq];
                long long a3 = pW2q[wv][192 | cq];
                while (tm) gbatch8(W2Tq, tm, cm, wv << 5, cq << 2, a0, a1, a2, a3);
                pW2q[wv][cq]        = a0;
                pW2q[wv][64  | cq]  = a1;
                pW2q[wv][128 | cq]  = a2;
                pW2q[wv][192 | cq]  = a3;
            }
        } else {
            int e = wv - 8;
            uint tm = (uint)rfl((int)t1w[e]);
            if (tm) {
                uint cm = (uint)rfl((int)m1w[e]);
                long long a0 = pV1q[e][cq];
                long long a1 = pV1q[e][64  | cq];
                long long a2 = pV1q[e][128 | cq];
                long long a3 = pV1q[e][192 | cq];
                while (tm) gbatch8(V1q, tm, cm, e << 5, cq << 2, a0, a1, a2, a3);
                pV1q[e][cq]        = a0;
                pV1q[e][64  | cq]  = a1;
                pV1q[e][128 | cq]  = a2;
                pV1q[e][192 | cq]  = a3;
            }
        }
        __syncthreads();
        // ---- D: layer-2 update (waves 0-3) + wx(t+1) (waves 4-7) + x prefetch (wave 8) ----
        if (tid < HH) {
            long long a1 = pW2q[0][tid] + pW2q[1][tid] + pW2q[2][tid] + pW2q[3][tid]
                         + pW2q[4][tid] + pW2q[5][tid] + pW2q[6][tid] + pW2q[7][tid];
            long long a2 = pV2q[0][tid] + pV2q[1][tid] + pV2q[2][tid] + pV2q[3][tid]
                         + pV2q[4][tid] + pV2q[5][tid] + pV2q[6][tid] + pV2q[7][tid];
            float gA = (float)((double)a1 * INV30);
            float gB = (float)((double)a2 * INV30);
            syn2 = fmaf(0.95f, syn2, b2r + gA + gB);
            mem2 = fmaf(beta2r, mem2, syn2) - (spk2 ? 1.f : 0.f);
            spk2 = mem2 > 1.0f;
            ull bal = __ballot(spk2 ? 1 : 0);
            if (cq == 0) {
                uint n0 = (uint)bal, n1 = (uint)(bal >> 32);
                t2w[2*wv]   = m2w[2*wv]   ^ n0;
                t2w[2*wv+1] = m2w[2*wv+1] ^ n1;
                m2w[2*wv]   = n0;
                m2w[2*wv+1] = n1;
            }
        } else if (tid < 2 * HH) {
            if ((t + 1) < TT) {
                int j2 = tid - HH;
                const float* xx = xts[(t + 1) & 1];
                float wx = b1r2;
#pragma unroll
                for (int f = 0; f < FF; ++f) wx = fmaf(xx[f], w1t_s[f * HH + j2], wx);
                wx_s[(t + 1) & 1][j2] = wx;
            }
        } else if (wv == 8 && cq < FF) {
            if ((t + 2) < TT) xts[t & 1][cq] = xg[(size_t)(t + 2) * FF + cq];
        }
        __syncthreads();
        // ---- E: toggle-updates on t2: WT drives (waves 0-7), V2 drives (waves 8-15) ----
        if (wv < 8) {
            uint tm = (uint)rfl((int)t2w[wv]);
            if (tm) {
                uint cm = (uint)rfl((int)m2w[wv]);
                long long a0 = pOq[wv][cq];
                long long a1 = pOq[wv][64  | cq];
                long long a2 = pOq[wv][128 | cq];
                long long a3 = pOq[wv][192 | cq];
                while (tm) gbatch8(WTq, tm, cm, wv << 5, cq << 2, a0, a1, a2, a3);
                pOq[wv][cq]        = a0;
                pOq[wv][64  | cq]  = a1;
                pOq[wv][128 | cq]  = a2;
                pOq[wv][192 | cq]  = a3;
            }
        } else {
            int e = wv - 8;
            uint tm = (uint)rfl((int)t2w[e]);
            if (tm) {
                uint cm = (uint)rfl((int)m2w[e]);
                long long a0 = pV2q[e][cq];
                long long a1 = pV2q[e][64  | cq];
                long long a2 = pV2q[e][128 | cq];
                long long a3 = pV2q[e][192 | cq];
                while (tm) gbatch8(V2q, tm, cm, e << 5, cq << 2, a0, a1, a2, a3);
                pV2q[e][cq]        = a0;
                pV2q[e][64  | cq]  = a1;
                pV2q[e][128 | cq]  = a2;
                pV2q[e][192 | cq]  = a3;
            }
        }
        __syncthreads();
        // ---- F: output layer (wave 15; overlaps B(t+1) on waves 0-3) ----
        if (wv == 15) {
            float mmax = -3.402823466e38f;
#pragma unroll
            for (int r = 0; r < 4; ++r) {
                int o = cq + (r << 6);
                if (o < OO) {
                    long long a = pOq[0][o] + pOq[1][o] + pOq[2][o] + pOq[3][o]
                                + pOq[4][o] + pOq[5][o] + pOq[6][o] + pOq[7][o];
                    float ot = (float)((double)a * INV30);
                    synO[r] = fmaf(aOr[r], synO[r], ot);
                    memO[r] = fmaf(bOr[r], memO[r], synO[r]) - (spkO[r] ? 1.f : 0.f);
                    spkO[r] = memO[r] > 1.0f;
                    mmax = fmaxf(mmax, memO[r]);
                }
            }
#pragma unroll
            for (int off = 32; off; off >>= 1) mmax = fmaxf(mmax, __shfl_xor(mmax, off, 64));
            float ex[4]; float se = 0.f;
#pragma unroll
            for (int r = 0; r < 4; ++r) {
                int o = cq + (r << 6);
                ex[r] = (o < OO) ? expf(memO[r] - mmax) : 0.f;
                se += ex[r];
            }
#pragma unroll
            for (int off = 32; off; off >>= 1) se += __shfl_xor(se, off, 64);
            if (t > 10) {
#pragma unroll
                for (int r = 0; r < 4; ++r) accO[r] += ex[r] / se;
            }
        }
        // no barrier: pOq's next writers (E(t+1)) sit behind the D(t+1) barrier, which
        // wave 15 only reaches after finishing F(t).
    }

    if (wv == 15) {
#pragma unroll
        for (int r = 0; r < 4; ++r) {
            int o = cq + (r << 6);
            if (o < OO) out[(size_t)b * OO + o] = accO[r];
        }
    }
}

// one-shot prep: padded 257x256 int32 fixed-point (2^30) tables, zero diagonal
// (V1q/V2q), zero row 256. Columns PERMUTED: position q*4+c holds original
// column c*64+q (see note above snn_main).
__global__ void prep_kernel(const float* __restrict__ Vrec1, const float* __restrict__ Vrec2,
                            const float* __restrict__ W2, const float* __restrict__ Wout,
                            int* __restrict__ V1q, int* __restrict__ V2q,
                            int* __restrict__ W2Tq, int* __restrict__ WTq) {
    int idx = blockIdx.x * blockDim.x + threadIdx.x;   // 257*256 entries
    if (idx >= 257 * 256) return;
    int r = idx >> 8, i = idx & 255;
    int q = i >> 2, c = i & 3;
    int sc = (c << 6) | q;                 // original column this slot holds
    float v1 = 0.f, v2 = 0.f, w2 = 0.f, wo = 0.f;
    if (r < 256) {
        if (r != sc) { v1 = Vrec1[r * HH + sc]; v2 = Vrec2[r * HH + sc]; }
        w2 = W2[sc * HH + r];
        if (sc < OO) wo = Wout[sc * HH + r];
    }
    const float S = 1073741824.0f;   // 2^30
    V1q[idx]  = __float2int_rn(v1 * S);
    V2q[idx]  = __float2int_rn(v2 * S);
    W2Tq[idx] = __float2int_rn(w2 * S);
    WTq[idx]  = __float2int_rn(wo * S);
}

extern "C" void kernel_launch(void* const* d_in, const int* in_sizes, int n_in,
                              void* d_out, int out_size, void* d_ws, size_t ws_size,
                              hipStream_t stream) {
    const float* x       = (const float*)d_in[0];
    const float* W1      = (const float*)d_in[1];
    const float* b1      = (const float*)d_in[2];
    const float* Vrec1   = (const float*)d_in[3];
    const float* beta1   = (const float*)d_in[4];
    const float* W2      = (const float*)d_in[5];
    const float* b2      = (const float*)d_in[6];
    const float* Vrec2   = (const float*)d_in[7];
    const float* beta2   = (const float*)d_in[8];
    const float* Wout    = (const float*)d_in[9];
    const float* alpha_o = (const float*)d_in[10];
    const float* beta_o  = (const float*)d_in[11];

    const int TBL = 257 * 256;       // int32 per padded table
    int* V1q  = (int*)d_ws;
    int* V2q  = V1q + TBL;
    int* W2Tq = V2q + TBL;
    int* WTq  = W2Tq + TBL;          // total ~1.05 MB of ws

    prep_kernel<<<(TBL + 255) / 256, 256, 0, stream>>>(Vrec1, Vrec2, W2, Wout,
                                                       V1q, V2q, W2Tq, WTq);
    snn_main<<<128, 1024, 0, stream>>>(x, W1, b1, beta1, b2, beta2,
                                       V1q, V2q, W2Tq, WTq,
                                       alpha_o, beta_o, (float*)d_out);
}

// Round 11
// 2913.143 us; speedup vs baseline: 2.3351x; 1.1949x over previous
//
#include <hip/hip_runtime.h>

#define TT 1000
#define FF 20
#define HH 256
#define OO 200
#define ZR 256           // zero-row index in padded int32 tables (257 rows x 256 cols)

typedef unsigned int uint;
typedef unsigned long long ull;

__device__ __forceinline__ int rfl(int v) { return __builtin_amdgcn_readfirstlane(v); }

#define INV30 9.31322574615478515625e-10   // 2^-30, exact in double

// ---- scalarized signed toggle batches (no arrays -> SROA, no scratch spill) ----
// Row from wave-uniform toggle word m; sign from current mask cur. Empty slots -> ZR.
#define GS(r, s) { int bb = __ffs((int)m); int k = (bb ? bb : 1) - 1;            \
                   r = rfl(m ? (rowbase + k) : ZR);                               \
                   s = rfl(m ? (int)((cur >> k) & 1u) : 1) ? 0 : -1;              \
                   m &= (m - 1u); }
#define GL(v, r) int4 v = *(const int4*)(tab + ((size_t)r << 8) + cx);
#define GA(v, s) { a0 += (long long)((v.x ^ s) - s); a1 += (long long)((v.y ^ s) - s); \
                   a2 += (long long)((v.z ^ s) - s); a3 += (long long)((v.w ^ s) - s); }

__device__ __forceinline__ void gb16(const int* __restrict__ tab, uint& m, uint cur,
                                     int rowbase, int cx,
                                     long long& a0, long long& a1, long long& a2, long long& a3) {
    int r0,r1,r2,r3,r4,r5,r6,r7,r8,r9,r10,r11,r12,r13,r14,r15;
    int s0,s1,s2,s3,s4,s5,s6,s7,s8,s9,s10,s11,s12,s13,s14,s15;
    GS(r0,s0) GS(r1,s1) GS(r2,s2) GS(r3,s3) GS(r4,s4) GS(r5,s5) GS(r6,s6) GS(r7,s7)
    GS(r8,s8) GS(r9,s9) GS(r10,s10) GS(r11,s11) GS(r12,s12) GS(r13,s13) GS(r14,s14) GS(r15,s15)
    GL(v0,r0) GL(v1,r1) GL(v2,r2) GL(v3,r3) GL(v4,r4) GL(v5,r5) GL(v6,r6) GL(v7,r7)
    GL(v8,r8) GL(v9,r9) GL(v10,r10) GL(v11,r11) GL(v12,r12) GL(v13,r13) GL(v14,r14) GL(v15,r15)
    GA(v0,s0) GA(v1,s1) GA(v2,s2) GA(v3,s3) GA(v4,s4) GA(v5,s5) GA(v6,s6) GA(v7,s7)
    GA(v8,s8) GA(v9,s9) GA(v10,s10) GA(v11,s11) GA(v12,s12) GA(v13,s13) GA(v14,s14) GA(v15,s15)
}

__device__ __forceinline__ void gb8(const int* __restrict__ tab, uint& m, uint cur,
                                    int rowbase, int cx,
                                    long long& a0, long long& a1, long long& a2, long long& a3) {
    int r0,r1,r2,r3,r4,r5,r6,r7, s0,s1,s2,s3,s4,s5,s6,s7;
    GS(r0,s0) GS(r1,s1) GS(r2,s2) GS(r3,s3) GS(r4,s4) GS(r5,s5) GS(r6,s6) GS(r7,s7)
    GL(v0,r0) GL(v1,r1) GL(v2,r2) GL(v3,r3) GL(v4,r4) GL(v5,r5) GL(v6,r6) GL(v7,r7)
    GA(v0,s0) GA(v1,s1) GA(v2,s2) GA(v3,s3) GA(v4,s4) GA(v5,s5) GA(v6,s6) GA(v7,s7)
}

__device__ __forceinline__ void gb4(const int* __restrict__ tab, uint& m, uint cur,
                                    int rowbase, int cx,
                                    long long& a0, long long& a1, long long& a2, long long& a3) {
    int r0,r1,r2,r3, s0,s1,s2,s3;
    GS(r0,s0) GS(r1,s1) GS(r2,s2) GS(r3,s3)
    GL(v0,r0) GL(v1,r1) GL(v2,r2) GL(v3,r3)
    GA(v0,s0) GA(v1,s1) GA(v2,s2) GA(v3,s3)
}

__device__ __forceinline__ void gatherA(const int* __restrict__ tab, uint m, uint cur,
                                        int rowbase, int cx,
                                        long long& a0, long long& a1, long long& a2, long long& a3) {
    while (m) {
        int pc = rfl(__popc(m));
        if (pc > 8)      gb16(tab, m, cur, rowbase, cx, a0, a1, a2, a3);
        else if (pc > 4) gb8(tab, m, cur, rowbase, cx, a0, a1, a2, a3);
        else             gb4(tab, m, cur, rowbase, cx, a0, a1, a2, a3);
    }
}

// Tables are column-PERMUTED in prep: position q*4+c holds original column c*64+q,
// so lane q's int4 load yields original columns {q, 64+q, 128+q, 192+q} -> LDS
// partial update (slot c*64+q) and consumer read (slot j) are both 8B lane-stride.

__global__ __launch_bounds__(1024) void snn_main(
    const float* __restrict__ x,
    const float* __restrict__ W1, const float* __restrict__ b1,
    const float* __restrict__ beta1,
    const float* __restrict__ b2, const float* __restrict__ beta2,
    const int* __restrict__ V1q, const int* __restrict__ V2q,
    const int* __restrict__ W2Tq, const int* __restrict__ WTq,
    const float* __restrict__ alpha_out, const float* __restrict__ beta_out,
    float* __restrict__ out)
{
    __shared__ float w1t_s[FF * HH];     // W1 transposed [f][h]
    __shared__ float wx_s[2][HH];        // b1 + W1 x_t, double-buffered by t parity
    __shared__ float xts[2][FF];         // x[t] double buffer
    __shared__ long long pW2q[8][HH];    // persistent int64 drive partials, in-place
    __shared__ long long pV1q[8][HH];
    __shared__ long long pV2q[8][HH];
    __shared__ long long pOq[8][HH];
    __shared__ uint m1w[8], t1w[8];      // current + toggle masks (8 x 32-bit words)
    __shared__ uint m2w[8], t2w[8];
    __shared__ float oRedM[4], oRedS[4]; // per-wave online-softmax stats (max, sumexp)

    const int tid = threadIdx.x;
    const int wv  = tid >> 6;
    const int cq  = tid & 63;
    const int b   = blockIdx.x;
    const float* xg = x + (size_t)b * TT * FF;

    // ---- init ----
    for (int idx = tid; idx < FF * HH; idx += 1024) {
        int h = idx / FF, f = idx - h * FF;
        w1t_s[f * HH + h] = W1[idx];
    }
    if (tid < FF) { xts[0][tid] = xg[tid]; xts[1][tid] = xg[FF + tid]; }
    if (tid < 8) { m1w[tid] = 0u; t1w[tid] = 0u; m2w[tid] = 0u; t2w[tid] = 0u; }
    for (int idx = tid; idx < 8 * HH; idx += 1024) {
        ((long long*)pW2q)[idx] = 0; ((long long*)pV1q)[idx] = 0;
        ((long long*)pV2q)[idx] = 0; ((long long*)pOq)[idx]  = 0;
    }

    float syn1 = 0.f, mem1 = 0.f, syn2 = 0.f, mem2 = 0.f;
    float b2r = 0.f, beta1r = 0.f, beta2r = 0.f;
    bool spk1 = false, spk2 = false;
    if (tid < HH) { beta1r = beta1[tid]; beta2r = beta2[tid]; b2r = b2[tid]; }
    float b1r2 = 0.f;
    if (tid >= HH && tid < 2 * HH) b1r2 = b1[tid - HH];

    // output-layer state: waves 4-7, one output per lane (o = tid - 256)
    const int oo = tid - 256;                       // valid for waves 4-7
    const bool oAct = (wv >= 4 && wv < 8 && oo < OO);
    float synO = 0.f, memO = 0.f, accO = 0.f, spkO = 0.f, eW = 0.f, mWown = 0.f;
    float aOr = 0.f, bOr = 0.f;
    if (oAct) { aOr = alpha_out[oo]; bOr = beta_out[oo]; }
    __syncthreads();
    if (tid < HH) {   // wx for t=0
        float wx = b1[tid];
#pragma unroll
        for (int f = 0; f < FF; ++f) wx = fmaf(xts[0][f], w1t_s[f * HH + tid], wx);
        wx_s[0][tid] = wx;
    }
    __syncthreads();

    uint tm1 = 0, cm1 = 0;   // waves 8-15: t1/m1 word cached from C for D's V1 gather

    for (int t = 0; t < TT; ++t) {
        // ---- B: L1 update (waves 0-3) | F1 for step t-1 (waves 4-7) ----
        if (tid < HH) {
            long long a = pV1q[0][tid] + pV1q[1][tid] + pV1q[2][tid] + pV1q[3][tid]
                        + pV1q[4][tid] + pV1q[5][tid] + pV1q[6][tid] + pV1q[7][tid];
            float g1 = (float)((double)a * INV30);
            syn1 = fmaf(0.95f, syn1, wx_s[t & 1][tid] + g1);
            mem1 = fmaf(beta1r, mem1, syn1) - (spk1 ? 1.f : 0.f);
            spk1 = mem1 > 1.0f;
            ull bal = __ballot(spk1 ? 1 : 0);
            if (cq == 0) {
                uint n0 = (uint)bal, n1 = (uint)(bal >> 32);
                t1w[2*wv]   = m1w[2*wv]   ^ n0;
                t1w[2*wv+1] = m1w[2*wv+1] ^ n1;
                m1w[2*wv]   = n0;
                m1w[2*wv+1] = n1;
            }
        } else if (wv < 8 && t > 0) {
            float ot = 0.f;
            if (oAct) {
                long long a = pOq[0][oo] + pOq[1][oo] + pOq[2][oo] + pOq[3][oo]
                            + pOq[4][oo] + pOq[5][oo] + pOq[6][oo] + pOq[7][oo];
                ot = (float)((double)a * INV30);
                synO = fmaf(aOr, synO, ot);
                memO = fmaf(bOr, memO, synO) - spkO;
                spkO = (memO > 1.0f) ? 1.f : 0.f;
            }
            float mloc = oAct ? memO : -3.402823466e38f;
#pragma unroll
            for (int off = 32; off; off >>= 1) mloc = fmaxf(mloc, __shfl_xor(mloc, off, 64));
            mWown = mloc;
            eW = oAct ? expf(memO - mWown) : 0.f;
            float sW = eW;
#pragma unroll
            for (int off = 32; off; off >>= 1) sW += __shfl_xor(sW, off, 64);
            if (cq == 0) { oRedM[wv - 4] = mWown; oRedS[wv - 4] = sW; }
        }
        __syncthreads();
        // ---- C: W2T gather on t1 (waves 8-15) | F2 (waves 4-7) ----
        if (wv >= 8) {
            int w = wv - 8;
            tm1 = (uint)rfl((int)t1w[w]);
            cm1 = (uint)rfl((int)m1w[w]);
            if (tm1) {
                const int* tab = W2Tq; int rowbase = w << 5; int cx = cq << 2;
                long long a0 = pW2q[w][cq];
                long long a1 = pW2q[w][64  | cq];
                long long a2 = pW2q[w][128 | cq];
                long long a3 = pW2q[w][192 | cq];
                uint m = tm1;
                gatherA(tab, m, cm1, rowbase, cx, a0, a1, a2, a3);
                pW2q[w][cq]       = a0;
                pW2q[w][64  | cq] = a1;
                pW2q[w][128 | cq] = a2;
                pW2q[w][192 | cq] = a3;
            }
        } else if (wv >= 4 && t > 0) {
            float m0 = oRedM[0], m1_ = oRedM[1], m2_ = oRedM[2], m3 = oRedM[3];
            float s0 = oRedS[0], s1 = oRedS[1], s2 = oRedS[2], s3 = oRedS[3];
            float gm = fmaxf(fmaxf(m0, m1_), fmaxf(m2_, m3));
            float se = s0 * expf(m0 - gm) + s1 * expf(m1_ - gm)
                     + s2 * expf(m2_ - gm) + s3 * expf(m3 - gm);
            if (oAct && (t - 1) > 10) {
                float ex = eW * expf(mWown - gm);
                accO += ex / se;
            }
        }
        __syncthreads();
        // ---- D: L2 update (0-3) | wx(t+1) (4-7) | V1 gather on cached t1 (8-15) ----
        if (tid < HH) {
            long long a1 = pW2q[0][tid] + pW2q[1][tid] + pW2q[2][tid] + pW2q[3][tid]
                         + pW2q[4][tid] + pW2q[5][tid] + pW2q[6][tid] + pW2q[7][tid];
            long long a2 = pV2q[0][tid] + pV2q[1][tid] + pV2q[2][tid] + pV2q[3][tid]
                         + pV2q[4][tid] + pV2q[5][tid] + pV2q[6][tid] + pV2q[7][tid];
            float gA = (float)((double)a1 * INV30);
            float gB = (float)((double)a2 * INV30);
            syn2 = fmaf(0.95f, syn2, b2r + gA + gB);
            mem2 = fmaf(beta2r, mem2, syn2) - (spk2 ? 1.f : 0.f);
            spk2 = mem2 > 1.0f;
            ull bal = __ballot(spk2 ? 1 : 0);
            if (cq == 0) {
                uint n0 = (uint)bal, n1 = (uint)(bal >> 32);
                t2w[2*wv]   = m2w[2*wv]   ^ n0;
                t2w[2*wv+1] = m2w[2*wv+1] ^ n1;
                m2w[2*wv]   = n0;
                m2w[2*wv+1] = n1;
            }
        } else if (wv < 8) {
            if ((t + 1) < TT) {
                int j2 = tid - HH;
                const float* xx = xts[(t + 1) & 1];
                float wx = b1r2;
#pragma unroll
                for (int f = 0; f < FF; ++f) wx = fmaf(xx[f], w1t_s[f * HH + j2], wx);
                wx_s[(t + 1) & 1][j2] = wx;
            }
        } else {
            int w = wv - 8;
            if (w == 0 && cq < FF && (t + 2) < TT)
                xts[t & 1][cq] = xg[(size_t)(t + 2) * FF + cq];
            if (tm1) {
                long long a0 = pV1q[w][cq];
                long long a1 = pV1q[w][64  | cq];
                long long a2 = pV1q[w][128 | cq];
                long long a3 = pV1q[w][192 | cq];
                uint m = tm1;
                gatherA(V1q, m, cm1, w << 5, cq << 2, a0, a1, a2, a3);
                pV1q[w][cq]       = a0;
                pV1q[w][64  | cq] = a1;
                pV1q[w][128 | cq] = a2;
                pV1q[w][192 | cq] = a3;
            }
        }
        __syncthreads();
        // ---- E: WT gather on t2 (waves 0-7) | V2 gather on t2 (waves 8-15) ----
        if (wv < 8) {
            uint tm = (uint)rfl((int)t2w[wv]);
            if (tm) {
                uint cm = (uint)rfl((int)m2w[wv]);
                long long a0 = pOq[wv][cq];
                long long a1 = pOq[wv][64  | cq];
                long long a2 = pOq[wv][128 | cq];
                long long a3 = pOq[wv][192 | cq];
                gatherA(WTq, tm, cm, wv << 5, cq << 2, a0, a1, a2, a3);
                pOq[wv][cq]       = a0;
                pOq[wv][64  | cq] = a1;
                pOq[wv][128 | cq] = a2;
                pOq[wv][192 | cq] = a3;
            }
        } else {
            int w = wv - 8;
            uint tm = (uint)rfl((int)t2w[w]);
            if (tm) {
                uint cm = (uint)rfl((int)m2w[w]);
                long long a0 = pV2q[w][cq];
                long long a1 = pV2q[w][64  | cq];
                long long a2 = pV2q[w][128 | cq];
                long long a3 = pV2q[w][192 | cq];
                gatherA(V2q, tm, cm, w << 5, cq << 2, a0, a1, a2, a3);
                pV2q[w][cq]       = a0;
                pV2q[w][64  | cq] = a1;
                pV2q[w][128 | cq] = a2;
                pV2q[w][192 | cq] = a3;
            }
        }
        __syncthreads();
    }

    // ---- drain: F1 + F2 for the final step (tp = TT-1 > 10) ----
    if (wv >= 4 && wv < 8) {
        float ot = 0.f;
        if (oAct) {
            long long a = pOq[0][oo] + pOq[1][oo] + pOq[2][oo] + pOq[3][oo]
                        + pOq[4][oo] + pOq[5][oo] + pOq[6][oo] + pOq[7][oo];
            ot = (float)((double)a * INV30);
            synO = fmaf(aOr, synO, ot);
            memO = fmaf(bOr, memO, synO) - spkO;
            spkO = (memO > 1.0f) ? 1.f : 0.f;
        }
        float mloc = oAct ? memO : -3.402823466e38f;
#pragma unroll
        for (int off = 32; off; off >>= 1) mloc = fmaxf(mloc, __shfl_xor(mloc, off, 64));
        mWown = mloc;
        eW = oAct ? expf(memO - mWown) : 0.f;
        float sW = eW;
#pragma unroll
        for (int off = 32; off; off >>= 1) sW += __shfl_xor(sW, off, 64);
        if (cq == 0) { oRedM[wv - 4] = mWown; oRedS[wv - 4] = sW; }
    }
    __syncthreads();
    if (oAct) {
        float m0 = oRedM[0], m1_ = oRedM[1], m2_ = oRedM[2], m3 = oRedM[3];
        float s0 = oRedS[0], s1 = oRedS[1], s2 = oRedS[2], s3 = oRedS[3];
        float gm = fmaxf(fmaxf(m0, m1_), fmaxf(m2_, m3));
        float se = s0 * expf(m0 - gm) + s1 * expf(m1_ - gm)
                 + s2 * expf(m2_ - gm) + s3 * expf(m3 - gm);
        float ex = eW * expf(mWown - gm);
        accO += ex / se;
        out[(size_t)b * OO + oo] = accO;
    }
}

// one-shot prep: padded 257x256 int32 fixed-point (2^30) tables, zero diagonal
// (V1q/V2q), zero row 256. Columns PERMUTED: position q*4+c holds original
// column c*64+q.
__global__ void prep_kernel(const float* __restrict__ Vrec1, const float* __restrict__ Vrec2,
                            const float* __restrict__ W2, const float* __restrict__ Wout,
                            int* __restrict__ V1q, int* __restrict__ V2q,
                            int* __restrict__ W2Tq, int* __restrict__ WTq) {
    int idx = blockIdx.x * blockDim.x + threadIdx.x;   // 257*256 entries
    if (idx >= 257 * 256) return;
    int r = idx >> 8, i = idx & 255;
    int q = i >> 2, c = i & 3;
    int sc = (c << 6) | q;                 // original column this slot holds
    float v1 = 0.f, v2 = 0.f, w2 = 0.f, wo = 0.f;
    if (r < 256) {
        if (r != sc) { v1 = Vrec1[r * HH + sc]; v2 = Vrec2[r * HH + sc]; }
        w2 = W2[sc * HH + r];
        if (sc < OO) wo = Wout[sc * HH + r];
    }
    const float S = 1073741824.0f;   // 2^30
    V1q[idx]  = __float2int_rn(v1 * S);
    V2q[idx]  = __float2int_rn(v2 * S);
    W2Tq[idx] = __float2int_rn(w2 * S);
    WTq[idx]  = __float2int_rn(wo * S);
}

extern "C" void kernel_launch(void* const* d_in, const int* in_sizes, int n_in,
                              void* d_out, int out_size, void* d_ws, size_t ws_size,
                              hipStream_t stream) {
    const float* x       = (const float*)d_in[0];
    const float* W1      = (const float*)d_in[1];
    const float* b1      = (const float*)d_in[2];
    const float* Vrec1   = (const float*)d_in[3];
    const float* beta1   = (const float*)d_in[4];
    const float* W2      = (const float*)d_in[5];
    const float* b2      = (const float*)d_in[6];
    const float* Vrec2   = (const float*)d_in[7];
    const float* beta2   = (const float*)d_in[8];
    const float* Wout    = (const float*)d_in[9];
    const float* alpha_o = (const float*)d_in[10];
    const float* beta_o  = (const float*)d_in[11];

    const int TBL = 257 * 256;       // int32 per padded table
    int* V1q  = (int*)d_ws;
    int* V2q  = V1q + TBL;
    int* W2Tq = V2q + TBL;
    int* WTq  = W2Tq + TBL;          // total ~1.05 MB of ws

    prep_kernel<<<(TBL + 255) / 256, 256, 0, stream>>>(Vrec1, Vrec2, W2, Wout,
                                                       V1q, V2q, W2Tq, WTq);
    snn_main<<<128, 1024, 0, stream>>>(x, W1, b1, beta1, b2, beta2,
                                       V1q, V2q, W2Tq, WTq,
                                       alpha_o, beta_o, (float*)d_out);
}